// Round 1
// baseline (4067.604 us; speedup 1.0000x reference)
//
#include <hip/hip_runtime.h>
#include <math.h>

#define T_ 64
#define B_ 256
#define D_ 16
#define S_ 64
#define H_ 128
#define O_ 8
#define NSTEP 63
#define NT 512

// RK tableau (stage 6 skipped: B_SOL[6]==0 and k6 unused)
__constant__ float c_A[6][5] = {
  {0.f, 0.f, 0.f, 0.f, 0.f},
  {0.161f, 0.f, 0.f, 0.f, 0.f},
  {-0.008480655492356989f, 0.335480655492357f, 0.f, 0.f, 0.f},
  {2.8971530571054935f, -6.359448489975075f, 4.3622954328695815f, 0.f, 0.f},
  {5.325864828439257f, -11.748883564062828f, 7.4955393428898365f, -0.09249506636175525f, 0.f},
  {5.86145544294642f, -12.92096931784711f, 8.159367898576159f, -0.071584973281401f, -0.028269050394068383f}
};
__constant__ float c_C[6] = {0.f, 0.161f, 0.327f, 0.9f, 0.9800255409045097f, 1.f};
__constant__ float c_Bw[6] = {0.09646076681806523f, 0.01f, 0.4798896504144996f,
                              1.379008574103742f, -3.290069515436081f, 2.324710524099774f};

__device__ __forceinline__ float softplus_f(float x) {
  // max(x,0) + log1p(exp(-|x|)) — matches jax.nn.softplus numerics
  return fmaxf(x, 0.f) + log1pf(__expf(-fabsf(x)));
}
__device__ __forceinline__ float tanh_f(float x) {
  float xc = fminf(fmaxf(x, -12.f), 12.f);
  float e = __expf(2.f * xc);
  return (e - 1.f) / (e + 1.f);
}

__global__ __launch_bounds__(NT) void cde_kernel(
    const float* __restrict__ ts,
    const float* __restrict__ coeff_d,
    const float* __restrict__ coeff_c,
    const float* __restrict__ coeff_b,
    const float* __restrict__ coeff_a,
    const float* __restrict__ Wi1, const float* __restrict__ bi1,
    const float* __restrict__ Wi2, const float* __restrict__ bi2,
    const float* __restrict__ Wf1, const float* __restrict__ bf1,
    const float* __restrict__ Wf2, const float* __restrict__ bf2,
    const float* __restrict__ Wf3, const float* __restrict__ bf3,
    const float* __restrict__ Wr, const float* __restrict__ br,
    float* __restrict__ out)
{
  // Transposed LDS layouts: lane i reads sW[k*H_+i] -> stride-1 across lanes,
  // conflict-free; broadcast on the shared activation.
  __shared__ float sWf1T[S_ * H_];   // 32 KB
  __shared__ float sWf2T[H_ * H_];   // 64 KB
  __shared__ float sbf1[H_], sbf2[H_];
  __shared__ float sbf3v[S_ * D_];   // 4 KB
  __shared__ float sy[S_], syj[S_];
  __shared__ float sk[6][S_];
  __shared__ float sh1[H_], sh2[H_];
  __shared__ float scb[D_], scc[D_], scd[D_], sdx[D_];

  const int tid = threadIdx.x;
  const int b = blockIdx.x;

  // ---- one-time staging ----
  for (int i = tid; i < H_ * S_; i += NT) {
    int h = i / S_, s = i - h * S_;
    sWf1T[s * H_ + h] = Wf1[i];
  }
  for (int i = tid; i < H_ * H_; i += NT) {
    int o = i / H_, k = i - o * H_;
    sWf2T[k * H_ + o] = Wf2[i];
  }
  if (tid < H_) { sbf1[tid] = bf1[tid]; sbf2[tid] = bf2[tid]; }
  for (int i = tid; i < S_ * D_; i += NT) sbf3v[i] = bf3[i];
  if (tid < D_) scb[tid] = coeff_a[((size_t)b * NSTEP + 0) * D_ + tid];  // x0
  __syncthreads();

  // ---- y0 = softplus(x0 @ Wi1^T + bi1) @ Wi2^T + bi2 ----
  if (tid < H_) {
    float acc = bi1[tid];
    #pragma unroll
    for (int d = 0; d < D_; d++) acc += scb[d] * Wi1[tid * D_ + d];
    sh1[tid] = softplus_f(acc);
  }
  __syncthreads();
  if (tid < S_) {
    float acc = bi2[tid];
    for (int h = 0; h < H_; h++) acc += sh1[h] * Wi2[tid * H_ + h];
    sy[tid] = acc;
  }
  __syncthreads();
  if (tid < O_) {
    float acc = br[tid];
    #pragma unroll
    for (int s = 0; s < S_; s++) acc += sy[s] * Wr[tid * S_ + s];
    out[(size_t)b * T_ * O_ + 0 * O_ + tid] = acc;
  }

  // ---- time loop ----
  for (int t = 0; t < NSTEP; t++) {
    float hstep = ts[t + 1] - ts[t];
    if (tid < D_) {
      size_t idx = ((size_t)b * NSTEP + t) * D_ + tid;
      scb[tid] = coeff_b[idx];
      scc[tid] = coeff_c[idx];
      scd[tid] = coeff_d[idx];
    }
    __syncthreads();

    for (int j = 0; j < 6; j++) {
      // stage input yj and dxdt
      if (tid < S_) {
        float acc = sy[tid];
        for (int m = 0; m < j; m++) acc += (hstep * c_A[j][m]) * sk[m][tid];
        syj[tid] = acc;
      } else if (tid < S_ + D_) {
        int d = tid - S_;
        float frac = c_C[j] * hstep;
        sdx[d] = scb[d] + frac * (2.f * scc[d] + 3.f * frac * scd[d]);
      }
      __syncthreads();

      // h1 = softplus(yj @ Wf1^T + bf1)
      if (tid < H_) {
        float a0 = 0.f, a1 = 0.f, a2 = 0.f, a3 = 0.f;
        #pragma unroll
        for (int s = 0; s < S_; s += 4) {
          a0 += syj[s + 0] * sWf1T[(s + 0) * H_ + tid];
          a1 += syj[s + 1] * sWf1T[(s + 1) * H_ + tid];
          a2 += syj[s + 2] * sWf1T[(s + 2) * H_ + tid];
          a3 += syj[s + 3] * sWf1T[(s + 3) * H_ + tid];
        }
        sh1[tid] = softplus_f(sbf1[tid] + (a0 + a1) + (a2 + a3));
      }
      __syncthreads();

      // h2 = softplus(h1 @ Wf2^T + bf2)
      if (tid < H_) {
        float a0 = 0.f, a1 = 0.f, a2 = 0.f, a3 = 0.f;
        #pragma unroll
        for (int k = 0; k < H_; k += 4) {
          a0 += sh1[k + 0] * sWf2T[(k + 0) * H_ + tid];
          a1 += sh1[k + 1] * sWf2T[(k + 1) * H_ + tid];
          a2 += sh1[k + 2] * sWf2T[(k + 2) * H_ + tid];
          a3 += sh1[k + 3] * sWf2T[(k + 3) * H_ + tid];
        }
        sh2[tid] = softplus_f(sbf2[tid] + (a0 + a1) + (a2 + a3));
      }
      __syncthreads();

      // k_j[s] = sum_d tanh(h2 . Wf3[s*16+d] + bf3) * dxdt[d]
      {
        int s = tid >> 3;
        int d0 = (tid & 7) << 1;
        float part = 0.f;
        #pragma unroll
        for (int rr = 0; rr < 2; rr++) {
          int r = s * D_ + d0 + rr;
          const float4* wp = (const float4*)(Wf3 + (size_t)r * H_);
          float a0 = 0.f, a1 = 0.f, a2 = 0.f, a3 = 0.f;
          #pragma unroll
          for (int kk = 0; kk < H_ / 4; kk++) {
            float4 w = wp[kk];
            a0 += w.x * sh2[4 * kk + 0];
            a1 += w.y * sh2[4 * kk + 1];
            a2 += w.z * sh2[4 * kk + 2];
            a3 += w.w * sh2[4 * kk + 3];
          }
          float dot = sbf3v[r] + (a0 + a1) + (a2 + a3);
          part += tanh_f(dot) * sdx[d0 + rr];
        }
        part += __shfl_down(part, 4, 8);
        part += __shfl_down(part, 2, 8);
        part += __shfl_down(part, 1, 8);
        if ((tid & 7) == 0) sk[j][s] = part;
      }
      __syncthreads();
    }

    // y += h * sum_j B[j] * k_j
    if (tid < S_) {
      float acc = 0.f;
      #pragma unroll
      for (int m = 0; m < 6; m++) acc += c_Bw[m] * sk[m][tid];
      sy[tid] += hstep * acc;
    }
    __syncthreads();

    // out[b, t+1, :] = y @ Wr^T + br
    if (tid < O_) {
      float acc = br[tid];
      #pragma unroll
      for (int s = 0; s < S_; s++) acc += sy[s] * Wr[tid * S_ + s];
      out[(size_t)b * T_ * O_ + (size_t)(t + 1) * O_ + tid] = acc;
    }
  }
}

extern "C" void kernel_launch(void* const* d_in, const int* in_sizes, int n_in,
                              void* d_out, int out_size, void* d_ws, size_t ws_size,
                              hipStream_t stream) {
  const float* ts  = (const float*)d_in[0];
  const float* cd  = (const float*)d_in[1];
  const float* cc  = (const float*)d_in[2];
  const float* cb  = (const float*)d_in[3];
  const float* ca  = (const float*)d_in[4];
  const float* Wi1 = (const float*)d_in[5];
  const float* bi1 = (const float*)d_in[6];
  const float* Wi2 = (const float*)d_in[7];
  const float* bi2 = (const float*)d_in[8];
  const float* Wf1 = (const float*)d_in[9];
  const float* bf1 = (const float*)d_in[10];
  const float* Wf2 = (const float*)d_in[11];
  const float* bf2 = (const float*)d_in[12];
  const float* Wf3 = (const float*)d_in[13];
  const float* bf3 = (const float*)d_in[14];
  const float* Wr  = (const float*)d_in[15];
  const float* br  = (const float*)d_in[16];

  hipLaunchKernelGGL(cde_kernel, dim3(B_), dim3(NT), 0, stream,
                     ts, cd, cc, cb, ca, Wi1, bi1, Wi2, bi2,
                     Wf1, bf1, Wf2, bf2, Wf3, bf3, Wr, br, (float*)d_out);
}

// Round 2
// 1066.503 us; speedup vs baseline: 3.8140x; 3.8140x over previous
//
#include <hip/hip_runtime.h>
#include <math.h>

typedef _Float16 half_t;
typedef _Float16 half2_t __attribute__((ext_vector_type(2)));
typedef _Float16 half8_t __attribute__((ext_vector_type(8)));

#define T_ 64
#define B_ 256
#define D_ 16
#define S_ 64
#define H_ 128
#define O_ 8
#define NSTEP 63
#define NT 512

// d_ws layout, in half elements
#define OFF3 0            // Wf3h row-major [1024][128]
#define N3   131072
#define OFF1 131072       // Wf1 packed pairs: [i*128+h] -> (Wf1[h][2i], Wf1[h][2i+1]), i<32
#define N1   8192
#define OFF2 139264       // Wf2 packed pairs: [i*128+o] -> (Wf2[o][2i], Wf2[o][2i+1]), i<64
#define N2   16384
#define NTOT 155648
#define WS_NEED (NTOT * 2)

// RK tableau (stage 6 skipped: B_SOL[6]==0 and k6 unused)
__constant__ float c_A[6][5] = {
  {0.f, 0.f, 0.f, 0.f, 0.f},
  {0.161f, 0.f, 0.f, 0.f, 0.f},
  {-0.008480655492356989f, 0.335480655492357f, 0.f, 0.f, 0.f},
  {2.8971530571054935f, -6.359448489975075f, 4.3622954328695815f, 0.f, 0.f},
  {5.325864828439257f, -11.748883564062828f, 7.4955393428898365f, -0.09249506636175525f, 0.f},
  {5.86145544294642f, -12.92096931784711f, 8.159367898576159f, -0.071584973281401f, -0.028269050394068383f}
};
__constant__ float c_C[6] = {0.f, 0.161f, 0.327f, 0.9f, 0.9800255409045097f, 1.f};
__constant__ float c_Bw[6] = {0.09646076681806523f, 0.01f, 0.4798896504144996f,
                              1.379008574103742f, -3.290069515436081f, 2.324710524099774f};

__device__ __forceinline__ float softplus_f(float x) {
  return fmaxf(x, 0.f) + log1pf(__expf(-fabsf(x)));
}
__device__ __forceinline__ float tanh_f(float x) {
  float xc = fminf(fmaxf(x, -12.f), 12.f);
  float e = __expf(2.f * xc);
  return (e - 1.f) / (e + 1.f);
}
__device__ __forceinline__ float fdot2_f(half2_t a, half2_t b, float c) {
#if __has_builtin(__builtin_amdgcn_fdot2)
  return __builtin_amdgcn_fdot2(a, b, c, false);
#else
  return c + (float)a[0] * (float)b[0] + (float)a[1] * (float)b[1];
#endif
}

// ---------------- prologue: fp32 -> fp16 weight conversion ----------------
__global__ __launch_bounds__(256) void convert_kernel(
    const float* __restrict__ Wf1, const float* __restrict__ Wf2,
    const float* __restrict__ Wf3, half_t* __restrict__ wsh)
{
  int q = blockIdx.x * 256 + threadIdx.x;
  if (q < N3) {
    wsh[q] = (half_t)Wf3[q];
  } else if (q < OFF2) {
    int r = q - OFF1, pair = r >> 1, p = r & 1;
    int i = pair >> 7, h = pair & 127;
    wsh[q] = (half_t)Wf1[h * S_ + 2 * i + p];
  } else if (q < NTOT) {
    int r = q - OFF2, pair = r >> 1, p = r & 1;
    int i = pair >> 7, o = pair & 127;
    wsh[q] = (half_t)Wf2[o * H_ + 2 * i + p];
  }
}

// ---------------- main fp16 kernel ----------------
__global__ __launch_bounds__(NT, 2) void cde_kernel_f16(
    const float* __restrict__ ts,
    const float* __restrict__ coeff_d,
    const float* __restrict__ coeff_c,
    const float* __restrict__ coeff_b,
    const float* __restrict__ coeff_a,
    const float* __restrict__ Wi1, const float* __restrict__ bi1,
    const float* __restrict__ Wi2, const float* __restrict__ bi2,
    const float* __restrict__ bf1, const float* __restrict__ bf2,
    const float* __restrict__ bf3,
    const float* __restrict__ Wr, const float* __restrict__ br,
    const half_t* __restrict__ wsh,
    float* __restrict__ out)
{
  __shared__ half2_t sWf1p[32 * H_];          // 16 KB
  __shared__ half2_t sWf2p[64 * H_];          // 32 KB
  __shared__ float sbf1[H_], sbf2[H_];
  __shared__ float sbf3v[S_ * D_];            // 4 KB
  __shared__ float sy[S_];
  __shared__ float sk[6][S_];
  __shared__ float sh1f[H_];
  __shared__ half_t syj_h[S_] __attribute__((aligned(16)));
  __shared__ half_t sh1h[H_] __attribute__((aligned(16)));
  __shared__ half_t sh2h[H_] __attribute__((aligned(16)));
  __shared__ float scb[D_], scc[D_], scd[D_], sdx[D_];

  const int tid = threadIdx.x;
  const int b = blockIdx.x;

  // ---- one-time staging: packed fp16 weights ws -> LDS ----
  {
    const float4* src1 = (const float4*)(wsh + OFF1);
    float4* dst1 = (float4*)sWf1p;
    for (int i = tid; i < 1024; i += NT) dst1[i] = src1[i];
    const float4* src2 = (const float4*)(wsh + OFF2);
    float4* dst2 = (float4*)sWf2p;
    for (int i = tid; i < 2048; i += NT) dst2[i] = src2[i];
  }
  if (tid < H_) { sbf1[tid] = bf1[tid]; sbf2[tid] = bf2[tid]; }
  for (int i = tid; i < S_ * D_; i += NT) sbf3v[i] = bf3[i];
  if (tid < D_) scb[tid] = coeff_a[((size_t)b * NSTEP + 0) * D_ + tid];  // x0
  __syncthreads();

  // ---- y0 = softplus(x0 @ Wi1^T + bi1) @ Wi2^T + bi2 (fp32, once) ----
  if (tid < H_) {
    float acc = bi1[tid];
    #pragma unroll
    for (int d = 0; d < D_; d++) acc += scb[d] * Wi1[tid * D_ + d];
    sh1f[tid] = softplus_f(acc);
  }
  __syncthreads();
  if (tid < S_) {
    float acc = bi2[tid];
    for (int h = 0; h < H_; h++) acc += sh1f[h] * Wi2[tid * H_ + h];
    sy[tid] = acc;
  }
  __syncthreads();
  if (tid < O_) {
    float acc = br[tid];
    #pragma unroll
    for (int s = 0; s < S_; s++) acc += sy[s] * Wr[tid * S_ + s];
    out[(size_t)b * T_ * O_ + tid] = acc;
  }

  // ---- time loop ----
  for (int t = 0; t < NSTEP; t++) {
    float hstep = ts[t + 1] - ts[t];
    if (tid < D_) {
      size_t idx = ((size_t)b * NSTEP + t) * D_ + tid;
      scb[tid] = coeff_b[idx];
      scc[tid] = coeff_c[idx];
      scd[tid] = coeff_d[idx];
    }
    __syncthreads();

    for (int j = 0; j < 6; j++) {
      // stage input yj (as fp16) and dxdt
      if (tid < S_) {
        float acc = sy[tid];
        for (int m = 0; m < j; m++) acc += (hstep * c_A[j][m]) * sk[m][tid];
        syj_h[tid] = (half_t)acc;
      } else if (tid < S_ + D_) {
        int d = tid - S_;
        float frac = c_C[j] * hstep;
        sdx[d] = scb[d] + frac * (2.f * scc[d] + 3.f * frac * scd[d]);
      }
      __syncthreads();

      // h1 = softplus(yj @ Wf1^T + bf1)  [fp16 dot2]
      if (tid < H_) {
        half2_t yv[32];
        const half8_t* yp = (const half8_t*)syj_h;
        #pragma unroll
        for (int ii = 0; ii < 8; ii++) {
          half8_t v = yp[ii];
          half2_t p0 = {v[0], v[1]}, p1 = {v[2], v[3]}, p2 = {v[4], v[5]}, p3 = {v[6], v[7]};
          yv[4*ii+0] = p0; yv[4*ii+1] = p1; yv[4*ii+2] = p2; yv[4*ii+3] = p3;
        }
        float a0 = 0.f, a1 = 0.f, a2 = 0.f, a3 = 0.f;
        #pragma unroll
        for (int i = 0; i < 32; i += 4) {
          a0 = fdot2_f(yv[i+0], sWf1p[(i+0) * H_ + tid], a0);
          a1 = fdot2_f(yv[i+1], sWf1p[(i+1) * H_ + tid], a1);
          a2 = fdot2_f(yv[i+2], sWf1p[(i+2) * H_ + tid], a2);
          a3 = fdot2_f(yv[i+3], sWf1p[(i+3) * H_ + tid], a3);
        }
        sh1h[tid] = (half_t)softplus_f(sbf1[tid] + (a0 + a1) + (a2 + a3));
      }
      __syncthreads();

      // h2 = softplus(h1 @ Wf2^T + bf2)  [fp16 dot2]
      if (tid < H_) {
        half2_t hv[64];
        const half8_t* hp = (const half8_t*)sh1h;
        #pragma unroll
        for (int ii = 0; ii < 16; ii++) {
          half8_t v = hp[ii];
          half2_t p0 = {v[0], v[1]}, p1 = {v[2], v[3]}, p2 = {v[4], v[5]}, p3 = {v[6], v[7]};
          hv[4*ii+0] = p0; hv[4*ii+1] = p1; hv[4*ii+2] = p2; hv[4*ii+3] = p3;
        }
        float a0 = 0.f, a1 = 0.f, a2 = 0.f, a3 = 0.f;
        #pragma unroll
        for (int i = 0; i < 64; i += 4) {
          a0 = fdot2_f(hv[i+0], sWf2p[(i+0) * H_ + tid], a0);
          a1 = fdot2_f(hv[i+1], sWf2p[(i+1) * H_ + tid], a1);
          a2 = fdot2_f(hv[i+2], sWf2p[(i+2) * H_ + tid], a2);
          a3 = fdot2_f(hv[i+3], sWf2p[(i+3) * H_ + tid], a3);
        }
        sh2h[tid] = (half_t)softplus_f(sbf2[tid] + (a0 + a1) + (a2 + a3));
      }
      __syncthreads();

      // k_j[s] = sum_d tanh(h2 . Wf3[s*16+d] + bf3) * dxdt[d]   [fp16 stream]
      {
        half2_t h2v[64];
        const half8_t* hp = (const half8_t*)sh2h;
        #pragma unroll
        for (int ii = 0; ii < 16; ii++) {
          half8_t v = hp[ii];
          half2_t p0 = {v[0], v[1]}, p1 = {v[2], v[3]}, p2 = {v[4], v[5]}, p3 = {v[6], v[7]};
          h2v[4*ii+0] = p0; h2v[4*ii+1] = p1; h2v[4*ii+2] = p2; h2v[4*ii+3] = p3;
        }
        int s = tid >> 3;
        int d0 = (tid & 7) << 1;
        float part = 0.f;
        #pragma unroll
        for (int rr = 0; rr < 2; rr++) {
          int r = s * D_ + d0 + rr;
          const half8_t* wp = (const half8_t*)(wsh + (size_t)r * H_);
          float a0 = 0.f, a1 = 0.f, a2 = 0.f, a3 = 0.f;
          #pragma unroll
          for (int kk = 0; kk < 16; kk++) {
            half8_t w = wp[kk];
            half2_t w0 = {w[0], w[1]}, w1 = {w[2], w[3]}, w2 = {w[4], w[5]}, w3 = {w[6], w[7]};
            a0 = fdot2_f(w0, h2v[4*kk+0], a0);
            a1 = fdot2_f(w1, h2v[4*kk+1], a1);
            a2 = fdot2_f(w2, h2v[4*kk+2], a2);
            a3 = fdot2_f(w3, h2v[4*kk+3], a3);
          }
          float dot = sbf3v[r] + (a0 + a1) + (a2 + a3);
          part += tanh_f(dot) * sdx[d0 + rr];
        }
        part += __shfl_down(part, 4, 8);
        part += __shfl_down(part, 2, 8);
        part += __shfl_down(part, 1, 8);
        if ((tid & 7) == 0) sk[j][s] = part;
      }
      __syncthreads();
    }

    // y += h * sum_j B[j] * k_j
    if (tid < S_) {
      float acc = 0.f;
      #pragma unroll
      for (int m = 0; m < 6; m++) acc += c_Bw[m] * sk[m][tid];
      sy[tid] += hstep * acc;
    }
    __syncthreads();

    // out[b, t+1, :] = y @ Wr^T + br
    if (tid < O_) {
      float acc = br[tid];
      #pragma unroll
      for (int s = 0; s < S_; s++) acc += sy[s] * Wr[tid * S_ + s];
      out[(size_t)b * T_ * O_ + (size_t)(t + 1) * O_ + tid] = acc;
    }
  }
}

// ---------------- fp32 fallback (round-1 kernel, used only if ws too small) ----------------
__global__ __launch_bounds__(NT) void cde_kernel_f32(
    const float* __restrict__ ts,
    const float* __restrict__ coeff_d,
    const float* __restrict__ coeff_c,
    const float* __restrict__ coeff_b,
    const float* __restrict__ coeff_a,
    const float* __restrict__ Wi1, const float* __restrict__ bi1,
    const float* __restrict__ Wi2, const float* __restrict__ bi2,
    const float* __restrict__ Wf1, const float* __restrict__ bf1,
    const float* __restrict__ Wf2, const float* __restrict__ bf2,
    const float* __restrict__ Wf3, const float* __restrict__ bf3,
    const float* __restrict__ Wr, const float* __restrict__ br,
    float* __restrict__ out)
{
  __shared__ float sWf1T[S_ * H_];
  __shared__ float sWf2T[H_ * H_];
  __shared__ float sbf1[H_], sbf2[H_];
  __shared__ float sbf3v[S_ * D_];
  __shared__ float sy[S_], syj[S_];
  __shared__ float sk[6][S_];
  __shared__ float sh1[H_], sh2[H_];
  __shared__ float scb[D_], scc[D_], scd[D_], sdx[D_];

  const int tid = threadIdx.x;
  const int b = blockIdx.x;

  for (int i = tid; i < H_ * S_; i += NT) {
    int h = i / S_, s = i - h * S_;
    sWf1T[s * H_ + h] = Wf1[i];
  }
  for (int i = tid; i < H_ * H_; i += NT) {
    int o = i / H_, k = i - o * H_;
    sWf2T[k * H_ + o] = Wf2[i];
  }
  if (tid < H_) { sbf1[tid] = bf1[tid]; sbf2[tid] = bf2[tid]; }
  for (int i = tid; i < S_ * D_; i += NT) sbf3v[i] = bf3[i];
  if (tid < D_) scb[tid] = coeff_a[((size_t)b * NSTEP + 0) * D_ + tid];
  __syncthreads();

  if (tid < H_) {
    float acc = bi1[tid];
    #pragma unroll
    for (int d = 0; d < D_; d++) acc += scb[d] * Wi1[tid * D_ + d];
    sh1[tid] = softplus_f(acc);
  }
  __syncthreads();
  if (tid < S_) {
    float acc = bi2[tid];
    for (int h = 0; h < H_; h++) acc += sh1[h] * Wi2[tid * H_ + h];
    sy[tid] = acc;
  }
  __syncthreads();
  if (tid < O_) {
    float acc = br[tid];
    #pragma unroll
    for (int s = 0; s < S_; s++) acc += sy[s] * Wr[tid * S_ + s];
    out[(size_t)b * T_ * O_ + tid] = acc;
  }

  for (int t = 0; t < NSTEP; t++) {
    float hstep = ts[t + 1] - ts[t];
    if (tid < D_) {
      size_t idx = ((size_t)b * NSTEP + t) * D_ + tid;
      scb[tid] = coeff_b[idx];
      scc[tid] = coeff_c[idx];
      scd[tid] = coeff_d[idx];
    }
    __syncthreads();

    for (int j = 0; j < 6; j++) {
      if (tid < S_) {
        float acc = sy[tid];
        for (int m = 0; m < j; m++) acc += (hstep * c_A[j][m]) * sk[m][tid];
        syj[tid] = acc;
      } else if (tid < S_ + D_) {
        int d = tid - S_;
        float frac = c_C[j] * hstep;
        sdx[d] = scb[d] + frac * (2.f * scc[d] + 3.f * frac * scd[d]);
      }
      __syncthreads();

      if (tid < H_) {
        float a0 = 0.f, a1 = 0.f, a2 = 0.f, a3 = 0.f;
        #pragma unroll
        for (int s = 0; s < S_; s += 4) {
          a0 += syj[s + 0] * sWf1T[(s + 0) * H_ + tid];
          a1 += syj[s + 1] * sWf1T[(s + 1) * H_ + tid];
          a2 += syj[s + 2] * sWf1T[(s + 2) * H_ + tid];
          a3 += syj[s + 3] * sWf1T[(s + 3) * H_ + tid];
        }
        sh1[tid] = softplus_f(sbf1[tid] + (a0 + a1) + (a2 + a3));
      }
      __syncthreads();

      if (tid < H_) {
        float a0 = 0.f, a1 = 0.f, a2 = 0.f, a3 = 0.f;
        #pragma unroll
        for (int k = 0; k < H_; k += 4) {
          a0 += sh1[k + 0] * sWf2T[(k + 0) * H_ + tid];
          a1 += sh1[k + 1] * sWf2T[(k + 1) * H_ + tid];
          a2 += sh1[k + 2] * sWf2T[(k + 2) * H_ + tid];
          a3 += sh1[k + 3] * sWf2T[(k + 3) * H_ + tid];
        }
        sh2[tid] = softplus_f(sbf2[tid] + (a0 + a1) + (a2 + a3));
      }
      __syncthreads();

      {
        int s = tid >> 3;
        int d0 = (tid & 7) << 1;
        float part = 0.f;
        #pragma unroll
        for (int rr = 0; rr < 2; rr++) {
          int r = s * D_ + d0 + rr;
          const float4* wp = (const float4*)(Wf3 + (size_t)r * H_);
          float a0 = 0.f, a1 = 0.f, a2 = 0.f, a3 = 0.f;
          #pragma unroll
          for (int kk = 0; kk < H_ / 4; kk++) {
            float4 w = wp[kk];
            a0 += w.x * sh2[4 * kk + 0];
            a1 += w.y * sh2[4 * kk + 1];
            a2 += w.z * sh2[4 * kk + 2];
            a3 += w.w * sh2[4 * kk + 3];
          }
          float dot = sbf3v[r] + (a0 + a1) + (a2 + a3);
          part += tanh_f(dot) * sdx[d0 + rr];
        }
        part += __shfl_down(part, 4, 8);
        part += __shfl_down(part, 2, 8);
        part += __shfl_down(part, 1, 8);
        if ((tid & 7) == 0) sk[j][s] = part;
      }
      __syncthreads();
    }

    if (tid < S_) {
      float acc = 0.f;
      #pragma unroll
      for (int m = 0; m < 6; m++) acc += c_Bw[m] * sk[m][tid];
      sy[tid] += hstep * acc;
    }
    __syncthreads();

    if (tid < O_) {
      float acc = br[tid];
      #pragma unroll
      for (int s = 0; s < S_; s++) acc += sy[s] * Wr[tid * S_ + s];
      out[(size_t)b * T_ * O_ + (size_t)(t + 1) * O_ + tid] = acc;
    }
  }
}

extern "C" void kernel_launch(void* const* d_in, const int* in_sizes, int n_in,
                              void* d_out, int out_size, void* d_ws, size_t ws_size,
                              hipStream_t stream) {
  const float* ts  = (const float*)d_in[0];
  const float* cd  = (const float*)d_in[1];
  const float* cc  = (const float*)d_in[2];
  const float* cb  = (const float*)d_in[3];
  const float* ca  = (const float*)d_in[4];
  const float* Wi1 = (const float*)d_in[5];
  const float* bi1 = (const float*)d_in[6];
  const float* Wi2 = (const float*)d_in[7];
  const float* bi2 = (const float*)d_in[8];
  const float* Wf1 = (const float*)d_in[9];
  const float* bf1 = (const float*)d_in[10];
  const float* Wf2 = (const float*)d_in[11];
  const float* bf2 = (const float*)d_in[12];
  const float* Wf3 = (const float*)d_in[13];
  const float* bf3 = (const float*)d_in[14];
  const float* Wr  = (const float*)d_in[15];
  const float* br  = (const float*)d_in[16];

  if (ws_size >= (size_t)WS_NEED) {
    half_t* wsh = (half_t*)d_ws;
    hipLaunchKernelGGL(convert_kernel, dim3(608), dim3(256), 0, stream,
                       Wf1, Wf2, Wf3, wsh);
    hipLaunchKernelGGL(cde_kernel_f16, dim3(B_), dim3(NT), 0, stream,
                       ts, cd, cc, cb, ca, Wi1, bi1, Wi2, bi2,
                       bf1, bf2, bf3, Wr, br, wsh, (float*)d_out);
  } else {
    hipLaunchKernelGGL(cde_kernel_f32, dim3(B_), dim3(NT), 0, stream,
                       ts, cd, cc, cb, ca, Wi1, bi1, Wi2, bi2,
                       Wf1, bf1, Wf2, bf2, Wf3, bf3, Wr, br, (float*)d_out);
  }
}

// Round 3
// 913.142 us; speedup vs baseline: 4.4545x; 1.1679x over previous
//
#include <hip/hip_runtime.h>
#include <math.h>

typedef _Float16 half_t;
typedef _Float16 half2_t __attribute__((ext_vector_type(2)));
typedef _Float16 half8_t __attribute__((ext_vector_type(8)));

#define T_ 64
#define B_ 256
#define D_ 16
#define S_ 64
#define H_ 128
#define O_ 8
#define NSTEP 63
#define NT 512

// ws layout (halves): Wf3 [1024][128] | Wf1 [128][64] | Wf2 [128][128], all row-major fp16
#define W3_OFF 0
#define W1_OFF 131072
#define W2_OFF 139264
#define WS_HALVES 155648
#define WS_NEED (WS_HALVES * 2)

// AE[j] = coefficients on k[0..j] producing the NEXT stage input (j<5) or the B_SOL row (j==5)
__device__ constexpr float AE[6][6] = {
  {0.161f, 0.f, 0.f, 0.f, 0.f, 0.f},
  {-0.008480655492356989f, 0.335480655492357f, 0.f, 0.f, 0.f, 0.f},
  {2.8971530571054935f, -6.359448489975075f, 4.3622954328695815f, 0.f, 0.f, 0.f},
  {5.325864828439257f, -11.748883564062828f, 7.4955393428898365f, -0.09249506636175525f, 0.f, 0.f},
  {5.86145544294642f, -12.92096931784711f, 8.159367898576159f, -0.071584973281401f, -0.028269050394068383f, 0.f},
  {0.09646076681806523f, 0.01f, 0.4798896504144996f, 1.379008574103742f, -3.290069515436081f, 2.324710524099774f}
};
__device__ constexpr float CCn[6] = {0.f, 0.161f, 0.327f, 0.9f, 0.9800255409045097f, 1.f};

__device__ __forceinline__ float softplus_f(float x) {
  return fmaxf(x, 0.f) + log1pf(__expf(-fabsf(x)));
}
__device__ __forceinline__ float tanh_f(float x) {
  float xc = fminf(fmaxf(x, -12.f), 12.f);
  float e = __expf(2.f * xc);
  return (e - 1.f) * __builtin_amdgcn_rcpf(e + 1.f);
}
__device__ __forceinline__ float fdot2_f(half2_t a, half2_t b, float c) {
#if __has_builtin(__builtin_amdgcn_fdot2)
  return __builtin_amdgcn_fdot2(a, b, c, false);
#else
  return c + (float)a[0] * (float)b[0] + (float)a[1] * (float)b[1];
#endif
}
__device__ __forceinline__ half2_t mk2(half_t a, half_t b) {
  half2_t r; r[0] = a; r[1] = b; return r;
}

// ---------------- prologue: fp32 -> fp16 weight conversion (row-major) ----------------
__global__ __launch_bounds__(256) void convert_kernel(
    const float* __restrict__ Wf1, const float* __restrict__ Wf2,
    const float* __restrict__ Wf3, half_t* __restrict__ wsh)
{
  int q = blockIdx.x * 256 + threadIdx.x;
  if (q < W1_OFF) wsh[q] = (half_t)Wf3[q];
  else if (q < W2_OFF) wsh[q] = (half_t)Wf1[q - W1_OFF];
  else if (q < WS_HALVES) wsh[q] = (half_t)Wf2[q - W2_OFF];
}

// ---------------- main kernel: register-resident weights ----------------
__global__ __launch_bounds__(NT, 2) void cde_kernel_f16(
    const float* __restrict__ ts,
    const float* __restrict__ coeff_d,
    const float* __restrict__ coeff_c,
    const float* __restrict__ coeff_b,
    const float* __restrict__ coeff_a,
    const float* __restrict__ Wi1, const float* __restrict__ bi1,
    const float* __restrict__ Wi2, const float* __restrict__ bi2,
    const float* __restrict__ bf1, const float* __restrict__ bf2,
    const float* __restrict__ bf3,
    const float* __restrict__ Wr, const float* __restrict__ br,
    const half_t* __restrict__ wsh,
    float* __restrict__ out)
{
  __shared__ __align__(16) half_t syj_h[S_];   // stage input y_j (fp16)
  __shared__ __align__(16) half_t sh1h[H_];
  __shared__ __align__(16) half_t sh2h[H_];
  __shared__ float syf[S_];                    // fp32 y for the out-projection
  __shared__ float sini[H_];
  __shared__ float sx0[D_];

  const int tid = threadIdx.x;
  const int b = blockIdx.x;
  // GEMV3 mapping: s-group si = tid>>3; within group L = tid&7:
  //   kq = L&3 -> K-quarter (32 halves), dh = L>>2 -> d-half (8 rows)
  const int L  = tid & 7;
  const int si = tid >> 3;
  const int kq = L & 3;
  const int dh = L >> 2;
  const int d0 = dh * 8 + kq * 2;   // the 2 d-indices this lane owns after the butterfly
  // h1/h2 mapping: output o4 = tid>>2, K-quarter q4 = tid&3
  const int o4 = tid >> 2;
  const int q4 = tid & 3;

  const half_t* __restrict__ w3 = wsh + W3_OFF;
  const half_t* __restrict__ w1 = wsh + W1_OFF;
  const half_t* __restrict__ w2 = wsh + W2_OFF;

  // ---- persistent weight registers (loaded once, used 378x) ----
  half8_t w3v[8][4];                 // 8 rows x 32-half K-quarter = 128 VGPRs
  #pragma unroll
  for (int i = 0; i < 8; ++i) {
    const half8_t* p = (const half8_t*)(w3 + ((si * 16 + dh * 8 + i) * H_ + kq * 32));
    w3v[i][0] = p[0]; w3v[i][1] = p[1]; w3v[i][2] = p[2]; w3v[i][3] = p[3];
  }
  half8_t w1v[2];                    // Wf1[o4][q4*16 .. +16)
  { const half8_t* p = (const half8_t*)(w1 + (o4 * S_ + q4 * 16)); w1v[0] = p[0]; w1v[1] = p[1]; }
  half8_t w2v[4];                    // Wf2[o4][q4*32 .. +32)
  { const half8_t* p = (const half8_t*)(w2 + (o4 * H_ + q4 * 32));
    w2v[0] = p[0]; w2v[1] = p[1]; w2v[2] = p[2]; w2v[3] = p[3]; }
  const float bf1r = bf1[o4];
  const float bf2r = bf2[o4];
  const float bf3a = bf3[si * D_ + d0];
  const float bf3b = bf3[si * D_ + d0 + 1];
  float wrr[8]; float brr = 0.f;
  if (tid < 64) {
    int oo = tid >> 3, sl = tid & 7;
    const float4* p = (const float4*)(Wr + oo * S_ + sl * 8);
    float4 u0 = p[0], u1 = p[1];
    wrr[0] = u0.x; wrr[1] = u0.y; wrr[2] = u0.z; wrr[3] = u0.w;
    wrr[4] = u1.x; wrr[5] = u1.y; wrr[6] = u1.z; wrr[7] = u1.w;
    brr = br[oo];
  }

  // ---- y0 = softplus(x0 @ Wi1^T + bi1) @ Wi2^T + bi2 (fp32, once) ----
  if (tid < D_) sx0[tid] = coeff_a[((size_t)b * NSTEP) * D_ + tid];
  __syncthreads();
  if (tid < H_) {
    float acc = bi1[tid];
    #pragma unroll
    for (int d = 0; d < D_; ++d) acc += sx0[d] * Wi1[tid * D_ + d];
    sini[tid] = softplus_f(acc);
  }
  __syncthreads();
  if (tid < S_) {
    float acc = bi2[tid];
    for (int h = 0; h < H_; ++h) acc += sini[h] * Wi2[tid * H_ + h];
    syf[tid] = acc;
  }
  __syncthreads();

  // leader lane (L==0) of each s-group keeps the fp32 state y[si] and k0..k5 in registers
  float syr = 0.f;
  float kr[6] = {0.f, 0.f, 0.f, 0.f, 0.f, 0.f};
  if (L == 0) { syr = syf[si]; syj_h[si] = (half_t)syr; }
  __syncthreads();

  // ---- time loop ----
  for (int t = 0; t < NSTEP; ++t) {
    const float hstep = ts[t + 1] - ts[t];
    const size_t cbase = ((size_t)b * NSTEP + t) * D_ + d0;
    const float2 vb = *(const float2*)(coeff_b + cbase);
    const float2 vc = *(const float2*)(coeff_c + cbase);
    const float2 vd = *(const float2*)(coeff_d + cbase);

    // out[b,t,:] from current y (syf) — overlapped with stage-0 h1 phase
    if (tid < 64) {
      int oo = tid >> 3, sl = tid & 7;
      float a = 0.f;
      #pragma unroll
      for (int i = 0; i < 8; ++i) a += syf[sl * 8 + i] * wrr[i];
      a += __shfl_down(a, 4, 8);
      a += __shfl_down(a, 2, 8);
      a += __shfl_down(a, 1, 8);
      if (sl == 0) out[((size_t)b * T_ + t) * O_ + oo] = a + brr;
    }

    #pragma unroll
    for (int j = 0; j < 6; ++j) {
      // ---- h1 = softplus(yj @ Wf1^T + bf1), split-K x4 ----
      {
        const half8_t* ap = (const half8_t*)(syj_h + q4 * 16);
        half8_t aa0 = ap[0], aa1 = ap[1];
        float acc = 0.f;
        #pragma unroll
        for (int p = 0; p < 4; ++p)
          acc = fdot2_f(mk2(w1v[0][2*p], w1v[0][2*p+1]), mk2(aa0[2*p], aa0[2*p+1]), acc);
        #pragma unroll
        for (int p = 0; p < 4; ++p)
          acc = fdot2_f(mk2(w1v[1][2*p], w1v[1][2*p+1]), mk2(aa1[2*p], aa1[2*p+1]), acc);
        acc += __shfl_xor(acc, 1);
        acc += __shfl_xor(acc, 2);
        if (q4 == 0) sh1h[o4] = (half_t)softplus_f(acc + bf1r);
      }
      __syncthreads();

      // ---- h2 = softplus(h1 @ Wf2^T + bf2), split-K x4 ----
      {
        const half8_t* ap = (const half8_t*)(sh1h + q4 * 32);
        float acc = 0.f;
        #pragma unroll
        for (int c = 0; c < 4; ++c) {
          half8_t v = ap[c];
          #pragma unroll
          for (int p = 0; p < 4; ++p)
            acc = fdot2_f(mk2(w2v[c][2*p], w2v[c][2*p+1]), mk2(v[2*p], v[2*p+1]), acc);
        }
        acc += __shfl_xor(acc, 1);
        acc += __shfl_xor(acc, 2);
        if (q4 == 0) sh2h[o4] = (half_t)softplus_f(acc + bf2r);
      }
      __syncthreads();

      // ---- GEMV3: k_j[si] = sum_d tanh(Wf3[si*16+d] . h2 + bf3) * dxdt[d] ----
      {
        float acc[8] = {0.f,0.f,0.f,0.f,0.f,0.f,0.f,0.f};
        const half8_t* ap = (const half8_t*)(sh2h + kq * 32);
        #pragma unroll
        for (int c = 0; c < 4; ++c) {
          half8_t v = ap[c];
          #pragma unroll
          for (int p = 0; p < 4; ++p) {
            half2_t av = mk2(v[2*p], v[2*p+1]);
            #pragma unroll
            for (int i = 0; i < 8; ++i)
              acc[i] = fdot2_f(mk2(w3v[i][c][2*p], w3v[i][c][2*p+1]), av, acc[i]);
          }
        }
        // butterfly K-reduce over the 4 kq lanes; lane ends owning rel-rows {2kq, 2kq+1}
        float tt[8];
        #pragma unroll
        for (int i = 0; i < 8; ++i) tt[i] = __shfl_xor(acc[i], 1);
        float n0 = (tid & 1) ? (acc[2] + tt[2]) : (acc[0] + tt[0]);
        float n1 = (tid & 1) ? (acc[3] + tt[3]) : (acc[1] + tt[1]);
        float n2 = (tid & 1) ? (acc[6] + tt[6]) : (acc[4] + tt[4]);
        float n3 = (tid & 1) ? (acc[7] + tt[7]) : (acc[5] + tt[5]);
        float u0 = __shfl_xor(n0, 2);
        float u1 = __shfl_xor(n1, 2);
        float u2 = __shfl_xor(n2, 2);
        float u3 = __shfl_xor(n3, 2);
        float f0 = (tid & 2) ? (n2 + u2) : (n0 + u0);
        float f1 = (tid & 2) ? (n3 + u3) : (n1 + u1);
        // dxdt for this lane's two d indices (all in registers)
        const float frac = CCn[j] * hstep;
        const float dxA = vb.x + frac * (2.f * vc.x + 3.f * frac * vd.x);
        const float dxB = vb.y + frac * (2.f * vc.y + 3.f * frac * vd.y);
        float part = tanh_f(f0 + bf3a) * dxA + tanh_f(f1 + bf3b) * dxB;
        part += __shfl_down(part, 4, 8);
        part += __shfl_down(part, 2, 8);
        part += __shfl_down(part, 1, 8);
        if (L == 0) {
          kr[j] = part;
          float sacc = 0.f;
          #pragma unroll
          for (int m = 0; m <= j; ++m) sacc += AE[j][m] * kr[m];
          if (j < 5) {
            syj_h[si] = (half_t)(syr + hstep * sacc);   // input of stage j+1
          } else {
            syr += hstep * sacc;                        // y_{t+1}
            syj_h[si] = (half_t)syr;                    // input of next timestep's stage 0
            syf[si] = syr;
          }
        }
      }
      __syncthreads();
    }
  }

  // final projection: out[b,63,:]
  if (tid < 64) {
    int oo = tid >> 3, sl = tid & 7;
    float a = 0.f;
    #pragma unroll
    for (int i = 0; i < 8; ++i) a += syf[sl * 8 + i] * wrr[i];
    a += __shfl_down(a, 4, 8);
    a += __shfl_down(a, 2, 8);
    a += __shfl_down(a, 1, 8);
    if (sl == 0) out[((size_t)b * T_ + (T_ - 1)) * O_ + oo] = a + brr;
  }
}

extern "C" void kernel_launch(void* const* d_in, const int* in_sizes, int n_in,
                              void* d_out, int out_size, void* d_ws, size_t ws_size,
                              hipStream_t stream) {
  const float* ts  = (const float*)d_in[0];
  const float* cd  = (const float*)d_in[1];
  const float* cc  = (const float*)d_in[2];
  const float* cb  = (const float*)d_in[3];
  const float* ca  = (const float*)d_in[4];
  const float* Wi1 = (const float*)d_in[5];
  const float* bi1 = (const float*)d_in[6];
  const float* Wi2 = (const float*)d_in[7];
  const float* bi2 = (const float*)d_in[8];
  const float* Wf1 = (const float*)d_in[9];
  const float* bf1 = (const float*)d_in[10];
  const float* Wf2 = (const float*)d_in[11];
  const float* bf2 = (const float*)d_in[12];
  const float* Wf3 = (const float*)d_in[13];
  const float* bf3 = (const float*)d_in[14];
  const float* Wr  = (const float*)d_in[15];
  const float* br  = (const float*)d_in[16];

  half_t* wsh = (half_t*)d_ws;
  hipLaunchKernelGGL(convert_kernel, dim3((WS_HALVES + 255) / 256), dim3(256), 0, stream,
                     Wf1, Wf2, Wf3, wsh);
  hipLaunchKernelGGL(cde_kernel_f16, dim3(B_), dim3(NT), 0, stream,
                     ts, cd, cc, cb, ca, Wi1, bi1, Wi2, bi2,
                     bf1, bf2, bf3, Wr, br, wsh, (float*)d_out);
}